// Round 2
// baseline (8003.163 us; speedup 1.0000x reference)
//
#include <hip/hip_runtime.h>
#include <hip/hip_bf16.h>
#include <cstdint>
#include <cstddef>

typedef __attribute__((ext_vector_type(8))) short bf16x8;
typedef __attribute__((ext_vector_type(4))) float f32x4;

// round-to-nearest-even f32 -> bf16 bits
__device__ __forceinline__ unsigned short f2bf(float f) {
  unsigned u = __float_as_uint(f);
  return (unsigned short)((u + 0x7fffu + ((u >> 16) & 1u)) >> 16);
}

// ---------------- transpose + cast: W[1024][4096] f32 -> WT[4096][1024] bf16
__global__ __launch_bounds__(256) void transpose_cast_k(const float* __restrict__ W,
                                                        unsigned short* __restrict__ WT) {
  __shared__ float tile[32][33];
  const int bn = blockIdx.x * 32, bk = blockIdx.y * 32;
  const int tx = threadIdx.x & 31, ty = threadIdx.x >> 5;  // ty 0..7
#pragma unroll
  for (int i = 0; i < 4; ++i) {
    const int k = ty + i * 8;
    tile[k][tx] = W[(size_t)(bk + k) * 4096 + bn + tx];
  }
  __syncthreads();
#pragma unroll
  for (int i = 0; i < 4; ++i) {
    const int n = ty + i * 8;
    WT[(size_t)(bn + n) * 1024 + bk + tx] = f2bf(tile[tx][n]);
  }
}

// ---------------- embedding gather -> bf16 [8192][1024]
__global__ __launch_bounds__(256) void embed_gather_k(const int* __restrict__ ids,
                                                      const float* __restrict__ emb,
                                                      unsigned short* __restrict__ x) {
  const int bt = blockIdx.x;
  const int id = ids[bt];
  const float4 v = ((const float4*)(emb + (size_t)id * 1024))[threadIdx.x];
  union { unsigned short u[4]; unsigned long long ll; } o;
  o.u[0] = f2bf(v.x); o.u[1] = f2bf(v.y); o.u[2] = f2bf(v.z); o.u[3] = f2bf(v.w);
  *(unsigned long long*)(x + (size_t)bt * 1024 + threadIdx.x * 4) = o.ll;
}

// ---------------- GEMM: C[M=8192][4096] f32 = A[M][1024] bf16 @ BT[4096][1024]^T + bias
__global__ __launch_bounds__(256) void gemm_bt_k(const unsigned short* __restrict__ A,
                                                 const unsigned short* __restrict__ BT,
                                                 const float* __restrict__ bias,
                                                 float* __restrict__ C) {
  __shared__ char sA[128 * 128];  // 128 rows x 64 bf16 (128B rows), XOR-swizzled
  __shared__ char sB[128 * 128];
  const int bid = blockIdx.x;
  const int bm = (bid >> 5) * 128;
  const int bn = (bid & 31) * 128;
  const int tid = threadIdx.x, lane = tid & 63;
  const int wv = tid >> 6, wm = wv >> 1, wn = wv & 1;
  const int lrow = lane & 15, lk = (lane >> 4) * 16;  // frag k byte offset
  f32x4 acc[4][4] = {};
  for (int kt = 0; kt < 16; ++kt) {
    const int k0 = kt * 64;
    bf16x8 av[4], bv[4];
#pragma unroll
    for (int i = 0; i < 4; ++i) {
      const int ch = i * 256 + tid;         // 0..1023
      const int row = ch >> 3, c = ch & 7;  // 16B chunk within row
      av[i] = *(const bf16x8*)(A + (size_t)(bm + row) * 1024 + k0 + c * 8);
      bv[i] = *(const bf16x8*)(BT + (size_t)(bn + row) * 1024 + k0 + c * 8);
    }
    __syncthreads();  // prior iter's LDS reads done
#pragma unroll
    for (int i = 0; i < 4; ++i) {
      const int ch = i * 256 + tid;
      const int row = ch >> 3, c = ch & 7;
      const int off = row * 128 + ((c * 16) ^ ((row & 7) << 4));
      *(bf16x8*)(sA + off) = av[i];
      *(bf16x8*)(sB + off) = bv[i];
    }
    __syncthreads();
#pragma unroll
    for (int kk = 0; kk < 2; ++kk) {
      bf16x8 af[4], bf_[4];
#pragma unroll
      for (int mi = 0; mi < 4; ++mi) {
        const int row = wm * 64 + mi * 16 + lrow;
        af[mi] = *(const bf16x8*)(sA + row * 128 + ((kk * 64 + lk) ^ ((row & 7) << 4)));
      }
#pragma unroll
      for (int ni = 0; ni < 4; ++ni) {
        const int row = wn * 64 + ni * 16 + lrow;
        bf_[ni] = *(const bf16x8*)(sB + row * 128 + ((kk * 64 + lk) ^ ((row & 7) << 4)));
      }
#pragma unroll
      for (int mi = 0; mi < 4; ++mi)
#pragma unroll
        for (int ni = 0; ni < 4; ++ni)
          acc[mi][ni] = __builtin_amdgcn_mfma_f32_16x16x32_bf16(af[mi], bf_[ni], acc[mi][ni], 0, 0, 0);
    }
  }
  const int cr0 = (lane >> 4) * 4;
#pragma unroll
  for (int mi = 0; mi < 4; ++mi)
#pragma unroll
    for (int ni = 0; ni < 4; ++ni) {
      const int col = bn + wn * 64 + ni * 16 + lrow;
      const float bb = bias[col];
#pragma unroll
      for (int r = 0; r < 4; ++r) {
        const int row = bm + wm * 64 + mi * 16 + cr0 + r;
        C[(size_t)row * 4096 + col] = acc[mi][ni][r] + bb;
      }
    }
}

// ---------------- per-group sync (release/acquire, agent scope)
__device__ __forceinline__ void group_sync(unsigned* ctr, unsigned target) {
  __builtin_amdgcn_fence(__ATOMIC_RELEASE, "agent");
  __syncthreads();
  if (threadIdx.x == 0) {
    __hip_atomic_fetch_add(ctr, 1u, __ATOMIC_RELAXED, __HIP_MEMORY_SCOPE_AGENT);
    while (__hip_atomic_load(ctr, __ATOMIC_RELAXED, __HIP_MEMORY_SCOPE_AGENT) < target)
      __builtin_amdgcn_s_sleep(2);
  }
  __syncthreads();
  __builtin_amdgcn_fence(__ATOMIC_ACQUIRE, "agent");
}

// ---------------- persistent LSTM layer (cooperative, 256 WGs x 256 thr)
// 4 batch-groups of 16 rows; each WG owns 16 units (64 Wh^T cols in LDS, swizzled)
template <int LAYER>
__global__ __launch_bounds__(256) void lstm_layer_k(
    const float* __restrict__ xp,            // [B*T][4096], row = b*128+t
    const unsigned short* __restrict__ WhT,  // [4096][1024] bf16
    const int* __restrict__ ids,             // [64][128]
    unsigned short* __restrict__ hbuf,       // [2][64][1024] bf16
    unsigned short* __restrict__ seqbf,      // layer0 out: [64][128][1024] bf16
    float* __restrict__ seqf,                // layer1 out: d_out seq f32
    float* __restrict__ hfin, float* __restrict__ cfin,
    unsigned* __restrict__ ctrs) {
  extern __shared__ __align__(16) char wlds[];  // 131072: 64 rows x 2048B, swizzled
  __shared__ float z_lds[4][16][17];
  const int tid = threadIdx.x, lane = tid & 63, gate = tid >> 6;
  const int wg = blockIdx.x;
  const int g = (wg & 7) >> 1;                // batch group 0..3
  const int w = (wg >> 3) * 2 + (wg & 1);     // 0..63 within group
  const int b0 = g * 16, u0 = w * 16;
  unsigned* ctr = ctrs + g * 32;              // 128B apart
  // stage this WG's 64 Wh^T rows into LDS (rows n: gate=n>>4, unit j=n&15)
  for (int i = 0; i < 32; ++i) {
    const int ch = i * 256 + tid;  // 0..8191 chunks of 16B
    const int n = ch >> 7, c = ch & 127;
    const int grow = (n >> 4) * 1024 + u0 + (n & 15);
    bf16x8 v = *(const bf16x8*)(WhT + (size_t)grow * 1024 + c * 8);
    *(bf16x8*)(wlds + n * 2048 + ((c * 16) ^ ((n & 7) << 4))) = v;
  }
  const int rrow = tid >> 4, du = tid & 15;
  const int brow = b0 + rrow, unit = u0 + du;
  float c_reg = 0.f, h_reg = 0.f;
  hbuf[(size_t)brow * 1024 + unit] = 0;  // zero h buffer 0
  group_sync(ctr, 64u);
  const int arow = b0 + (lane & 15);
  const int lk = (lane >> 4) * 16;
  const int n_ = gate * 16 + (lane & 15);
  const char* bbase = wlds + n_ * 2048;
  const int bxor = (n_ & 7) << 4;
  for (int t = 0; t < 128; ++t) {
    const int cur = t & 1;
    const char* habase = (const char*)hbuf + cur * 131072 + arow * 2048 + lk;
    f32x4 acc0 = {}, acc1 = {};
#pragma unroll 8
    for (int ks = 0; ks < 32; ks += 2) {
      bf16x8 a0 = *(const bf16x8*)(habase + ks * 64);
      bf16x8 bb0 = *(const bf16x8*)(bbase + ((ks * 64 + lk) ^ bxor));
      bf16x8 a1 = *(const bf16x8*)(habase + ks * 64 + 64);
      bf16x8 bb1 = *(const bf16x8*)(bbase + (((ks + 1) * 64 + lk) ^ bxor));
      acc0 = __builtin_amdgcn_mfma_f32_16x16x32_bf16(a0, bb0, acc0, 0, 0, 0);
      acc1 = __builtin_amdgcn_mfma_f32_16x16x32_bf16(a1, bb1, acc1, 0, 0, 0);
    }
    acc0 += acc1;
#pragma unroll
    for (int r = 0; r < 4; ++r) z_lds[gate][(lane >> 4) * 4 + r][lane & 15] = acc0[r];
    __syncthreads();
    const float* xr = xp + ((size_t)brow * 128 + t) * 4096 + unit;
    const float zi = z_lds[0][rrow][du] + xr[0];
    const float zf = z_lds[1][rrow][du] + xr[1024];
    const float zg = z_lds[2][rrow][du] + xr[2048];
    const float zo = z_lds[3][rrow][du] + xr[3072];
    const float ig = 1.f / (1.f + expf(-zi));
    const float fg = 1.f / (1.f + expf(-zf));
    const float gt = tanhf(zg);
    const float og = 1.f / (1.f + expf(-zo));
    const float cn = fg * c_reg + ig * gt;
    const float hn = og * tanhf(cn);
    if (ids[brow * 128 + t] != 0) { c_reg = cn; h_reg = hn; }
    const unsigned short hb = f2bf(h_reg);
    hbuf[(size_t)(cur ^ 1) * 65536 + (size_t)brow * 1024 + unit] = hb;
    if (LAYER == 0)
      seqbf[((size_t)brow * 128 + t) * 1024 + unit] = hb;
    else
      seqf[((size_t)brow * 128 + t) * 1024 + unit] = h_reg;
    group_sync(ctr, 64u * (t + 2));
  }
  hfin[(size_t)brow * 1024 + unit] = h_reg;
  cfin[(size_t)brow * 1024 + unit] = c_reg;
}

extern "C" void kernel_launch(void* const* d_in, const int* in_sizes, int n_in,
                              void* d_out, int out_size, void* d_ws, size_t ws_size,
                              hipStream_t stream) {
  (void)in_sizes; (void)n_in; (void)out_size; (void)ws_size;
  const int* ids = (const int*)d_in[0];
  const float* emb = (const float*)d_in[1];
  const float* Wx0 = (const float*)d_in[2];
  const float* Wh0 = (const float*)d_in[3];
  const float* b0 = (const float*)d_in[4];
  const float* Wx1 = (const float*)d_in[5];
  const float* Wh1 = (const float*)d_in[6];
  const float* b1 = (const float*)d_in[7];
  float* out = (float*)d_out;

  char* ws = (char*)d_ws;
  const size_t SZ_WT = (size_t)4096 * 1024 * 2;  // 8 MiB
  unsigned short* WxT0 = (unsigned short*)(ws);
  unsigned short* WhT0 = (unsigned short*)(ws + SZ_WT);
  unsigned short* WxT1 = (unsigned short*)(ws + 2 * SZ_WT);
  unsigned short* WhT1 = (unsigned short*)(ws + 3 * SZ_WT);
  unsigned short* xbf = (unsigned short*)(ws + 4 * SZ_WT);                   // 16 MiB
  unsigned short* seq0 = (unsigned short*)(ws + 4 * SZ_WT + 16777216);       // 16 MiB
  unsigned short* hbuf = (unsigned short*)(ws + 4 * SZ_WT + 2 * 16777216);   // 256 KiB
  unsigned* ctrs = (unsigned*)(ws + 4 * SZ_WT + 2 * 16777216 + 262144);      // 512 B
  float* xpb = (float*)(ws + 4 * SZ_WT + 2 * 16777216 + 262144 + 512);       // 128 MiB

  float* h0f = out + 8388608;
  float* c0f = h0f + 65536;
  float* h1f = c0f + 65536;
  float* c1f = h1f + 65536;

  transpose_cast_k<<<dim3(128, 32), dim3(256), 0, stream>>>(Wx0, WxT0);
  transpose_cast_k<<<dim3(128, 32), dim3(256), 0, stream>>>(Wh0, WhT0);
  transpose_cast_k<<<dim3(128, 32), dim3(256), 0, stream>>>(Wx1, WxT1);
  transpose_cast_k<<<dim3(128, 32), dim3(256), 0, stream>>>(Wh1, WhT1);
  embed_gather_k<<<dim3(8192), dim3(256), 0, stream>>>(ids, emb, xbf);
  gemm_bt_k<<<dim3(2048), dim3(256), 0, stream>>>(xbf, WxT0, b0, xpb);

  hipFuncSetAttribute(reinterpret_cast<const void*>(&lstm_layer_k<0>),
                      hipFuncAttributeMaxDynamicSharedMemorySize, 131072);
  hipFuncSetAttribute(reinterpret_cast<const void*>(&lstm_layer_k<1>),
                      hipFuncAttributeMaxDynamicSharedMemorySize, 131072);

  hipMemsetAsync(ctrs, 0, 512, stream);
  {
    const float* xp_p = xpb;
    const unsigned short* wht = WhT0;
    const int* ids_p = ids;
    unsigned short* hb_p = hbuf;
    unsigned short* sb_p = seq0;
    float* sf_p = nullptr;
    float* hf_p = h0f;
    float* cf_p = c0f;
    unsigned* ctr_p = ctrs;
    void* ka[9] = {&xp_p, &wht, &ids_p, &hb_p, &sb_p, &sf_p, &hf_p, &cf_p, &ctr_p};
    hipLaunchCooperativeKernel(reinterpret_cast<const void*>(&lstm_layer_k<0>),
                               dim3(256), dim3(256), ka, 131072u, stream);
  }
  gemm_bt_k<<<dim3(2048), dim3(256), 0, stream>>>(seq0, WxT1, b1, xpb);
  hipMemsetAsync(ctrs, 0, 512, stream);
  {
    const float* xp_p = xpb;
    const unsigned short* wht = WhT1;
    const int* ids_p = ids;
    unsigned short* hb_p = hbuf;
    unsigned short* sb_p = nullptr;
    float* sf_p = out;
    float* hf_p = h1f;
    float* cf_p = c1f;
    unsigned* ctr_p = ctrs;
    void* ka[9] = {&xp_p, &wht, &ids_p, &hb_p, &sb_p, &sf_p, &hf_p, &cf_p, &ctr_p};
    hipLaunchCooperativeKernel(reinterpret_cast<const void*>(&lstm_layer_k<1>),
                               dim3(256), dim3(256), ka, 131072u, stream);
  }
}

// Round 3
// 1387.778 us; speedup vs baseline: 5.7669x; 5.7669x over previous
//
#include <hip/hip_runtime.h>
#include <hip/hip_bf16.h>
#include <cstdint>
#include <cstddef>

typedef __attribute__((ext_vector_type(8))) short bf16x8;
typedef __attribute__((ext_vector_type(4))) float f32x4;
typedef __attribute__((ext_vector_type(4))) unsigned int u32x4;

// round-to-nearest-even f32 -> bf16 bits
__device__ __forceinline__ unsigned short f2bf(float f) {
  unsigned u = __float_as_uint(f);
  return (unsigned short)((u + 0x7fffu + ((u >> 16) & 1u)) >> 16);
}

// ---------------- transpose + cast: W[1024][4096] f32 -> WT[4096][1024] bf16
__global__ __launch_bounds__(256) void transpose_cast_k(const float* __restrict__ W,
                                                        unsigned short* __restrict__ WT) {
  __shared__ float tile[32][33];
  const int bn = blockIdx.x * 32, bk = blockIdx.y * 32;
  const int tx = threadIdx.x & 31, ty = threadIdx.x >> 5;  // ty 0..7
#pragma unroll
  for (int i = 0; i < 4; ++i) {
    const int k = ty + i * 8;
    tile[k][tx] = W[(size_t)(bk + k) * 4096 + bn + tx];
  }
  __syncthreads();
#pragma unroll
  for (int i = 0; i < 4; ++i) {
    const int n = ty + i * 8;
    WT[(size_t)(bn + n) * 1024 + bk + tx] = f2bf(tile[tx][n]);
  }
}

// ---------------- embedding gather -> bf16 [8192][1024]
__global__ __launch_bounds__(256) void embed_gather_k(const int* __restrict__ ids,
                                                      const float* __restrict__ emb,
                                                      unsigned short* __restrict__ x) {
  const int bt = blockIdx.x;
  const int id = ids[bt];
  const float4 v = ((const float4*)(emb + (size_t)id * 1024))[threadIdx.x];
  union { unsigned short u[4]; unsigned long long ll; } o;
  o.u[0] = f2bf(v.x); o.u[1] = f2bf(v.y); o.u[2] = f2bf(v.z); o.u[3] = f2bf(v.w);
  *(unsigned long long*)(x + (size_t)bt * 1024 + threadIdx.x * 4) = o.ll;
}

// ---------------- GEMM: C[M=8192][4096] f32 = A[M][1024] bf16 @ BT[4096][1024]^T + bias
__global__ __launch_bounds__(256) void gemm_bt_k(const unsigned short* __restrict__ A,
                                                 const unsigned short* __restrict__ BT,
                                                 const float* __restrict__ bias,
                                                 float* __restrict__ C) {
  __shared__ char sA[128 * 128];  // 128 rows x 64 bf16 (128B rows), XOR-swizzled
  __shared__ char sB[128 * 128];
  const int bid = blockIdx.x;
  const int bm = (bid >> 5) * 128;
  const int bn = (bid & 31) * 128;
  const int tid = threadIdx.x, lane = tid & 63;
  const int wv = tid >> 6, wm = wv >> 1, wn = wv & 1;
  const int lrow = lane & 15, lk = (lane >> 4) * 16;  // frag k byte offset
  f32x4 acc[4][4] = {};
  for (int kt = 0; kt < 16; ++kt) {
    const int k0 = kt * 64;
    bf16x8 av[4], bv[4];
#pragma unroll
    for (int i = 0; i < 4; ++i) {
      const int ch = i * 256 + tid;         // 0..1023
      const int row = ch >> 3, c = ch & 7;  // 16B chunk within row
      av[i] = *(const bf16x8*)(A + (size_t)(bm + row) * 1024 + k0 + c * 8);
      bv[i] = *(const bf16x8*)(BT + (size_t)(bn + row) * 1024 + k0 + c * 8);
    }
    __syncthreads();  // prior iter's LDS reads done
#pragma unroll
    for (int i = 0; i < 4; ++i) {
      const int ch = i * 256 + tid;
      const int row = ch >> 3, c = ch & 7;
      const int off = row * 128 + ((c * 16) ^ ((row & 7) << 4));
      *(bf16x8*)(sA + off) = av[i];
      *(bf16x8*)(sB + off) = bv[i];
    }
    __syncthreads();
#pragma unroll
    for (int kk = 0; kk < 2; ++kk) {
      bf16x8 af[4], bf_[4];
#pragma unroll
      for (int mi = 0; mi < 4; ++mi) {
        const int row = wm * 64 + mi * 16 + lrow;
        af[mi] = *(const bf16x8*)(sA + row * 128 + ((kk * 64 + lk) ^ ((row & 7) << 4)));
      }
#pragma unroll
      for (int ni = 0; ni < 4; ++ni) {
        const int row = wn * 64 + ni * 16 + lrow;
        bf_[ni] = *(const bf16x8*)(sB + row * 128 + ((kk * 64 + lk) ^ ((row & 7) << 4)));
      }
#pragma unroll
      for (int mi = 0; mi < 4; ++mi)
#pragma unroll
        for (int ni = 0; ni < 4; ++ni)
          acc[mi][ni] = __builtin_amdgcn_mfma_f32_16x16x32_bf16(af[mi], bf_[ni], acc[mi][ni], 0, 0, 0);
    }
  }
  const int cr0 = (lane >> 4) * 4;
#pragma unroll
  for (int mi = 0; mi < 4; ++mi)
#pragma unroll
    for (int ni = 0; ni < 4; ++ni) {
      const int col = bn + wn * 64 + ni * 16 + lrow;
      const float bb = bias[col];
#pragma unroll
      for (int r = 0; r < 4; ++r) {
        const int row = bm + wm * 64 + mi * 16 + cr0 + r;
        C[(size_t)row * 4096 + col] = acc[mi][ni][r] + bb;
      }
    }
}

// ---------------- persistent LSTM layer (cooperative, 256 WGs x 256 thr)
// 4 batch-groups of 16 rows; each WG owns 16 units, k-split across 4 waves.
// Sync: fence-free. h + flags go through LLC via sc0/sc1 bypass; per-WG epoch
// flags on distinct 64B lines; consumers poll 64 flags with one 64-lane gather.
template <int LAYER>
__global__ __launch_bounds__(256) void lstm_layer_k(
    const float* __restrict__ xp,            // [B*T][4096], row = b*128+t
    const unsigned short* __restrict__ WhT,  // [4096][1024] bf16
    const int* __restrict__ ids,             // [64][128]
    unsigned short* __restrict__ hbuf,       // [2][64][1024] bf16
    unsigned short* __restrict__ seqbf,      // layer0 out: [64][128][1024] bf16
    float* __restrict__ seqf,                // layer1 out: d_out seq f32
    float* __restrict__ hfin, float* __restrict__ cfin,
    unsigned* __restrict__ flags_all) {      // 4 groups x 1024 u32 (64 flags, 64B stride)
  extern __shared__ __align__(16) char dlds[];  // 131072 weights + 20480 zpart
  char* wlds = dlds;
  float* zp = (float*)(dlds + 131072);  // [16][16][20] f32: (wave*4+gate, row, unit)
  const int tid = threadIdx.x, lane = tid & 63, wave = tid >> 6;
  const int wg = blockIdx.x;
  const int g = wg & 3, w = wg >> 2;  // batch group, unit-group within group
  const int b0 = g * 16, u0 = w * 16;
  unsigned* flags = flags_all + g * 1024;

  // stage this WG's 64 Wh^T rows into LDS (rows n: gate=n>>4, unit j=n&15), XOR-swizzled
  for (int i = 0; i < 32; ++i) {
    const int ch = i * 256 + tid;  // 0..8191 chunks of 16B
    const int n = ch >> 7, c = ch & 127;
    const int grow = (n >> 4) * 1024 + u0 + (n & 15);
    bf16x8 v = *(const bf16x8*)(WhT + (size_t)grow * 1024 + c * 8);
    *(bf16x8*)(wlds + n * 2048 + ((c * 16) ^ ((n & 7) << 4))) = v;
  }
  const int rrow = tid >> 4, du = tid & 15;
  const int brow = b0 + rrow, unit = u0 + du;
  // publish h(0) = 0 into buf0 (LLC write-through)
  {
    unsigned short* p = hbuf + (size_t)brow * 1024 + unit;
    unsigned zv = 0;
    asm volatile("global_store_short %0, %1, off sc0 sc1" :: "v"(p), "v"(zv) : "memory");
  }
  asm volatile("s_waitcnt vmcnt(0)" ::: "memory");
  __syncthreads();  // also covers weight-staging LDS writes
  if (tid == 0)
    __hip_atomic_store(&flags[w * 16], 1u, __ATOMIC_RELAXED, __HIP_MEMORY_SCOPE_AGENT);

  float c_reg = 0.f, h_reg = 0.f;
  const int lr = lane & 15;             // A/B fragment row
  const int lkb = (lane >> 4) * 16;     // fragment k byte offset within 64B chunk
  const int wq = wave * 512;            // this wave's k-quarter byte offset (2048B row)

  for (int t = 0; t < 128; ++t) {
    // ---- prefetch xp + mask before the poll (HBM latency hides under sync)
    const float* xr = xp + ((size_t)brow * 128 + t) * 4096 + unit;
    const float x0 = xr[0], x1 = xr[1024], x2 = xr[2048], x3 = xr[3072];
    const int idv = ids[brow * 128 + t];
    // ---- poll: all 64 producer flags of this group >= t+1 (one gather/iter)
    {
      const unsigned* fp = flags + lane * 16;
      const unsigned target = (unsigned)(t + 1);
      for (;;) {
        unsigned v = __hip_atomic_load(fp, __ATOMIC_RELAXED, __HIP_MEMORY_SCOPE_AGENT);
        if (__all((int)(v >= target))) break;
        __builtin_amdgcn_s_sleep(1);
      }
    }
    // ---- load this wave's h k-quarter fragments (LLC-coherent)
    const char* hb = (const char*)hbuf + (size_t)(t & 1) * 131072 +
                     (size_t)(b0 + lr) * 2048 + wq + lkb;
    u32x4 araw[8];
#pragma unroll
    for (int c = 0; c < 8; ++c)
      asm volatile("global_load_dwordx4 %0, %1, off sc0 sc1"
                   : "=&v"(araw[c]) : "v"(hb + c * 64) : "memory");
    asm volatile("s_waitcnt vmcnt(0)" ::: "memory");
    __builtin_amdgcn_sched_barrier(0);
    // ---- 32 MFMA: 4 gates x 8 k-chunks of this wave's quarter
    f32x4 acc[4] = {};
#pragma unroll
    for (int gg = 0; gg < 4; ++gg) {
      const int n = gg * 16 + lr;
      const char* bb = wlds + n * 2048;
      const int bx = (n & 7) << 4;
#pragma unroll
      for (int c = 0; c < 8; ++c) {
        bf16x8 bfv = *(const bf16x8*)(bb + ((wq + c * 64 + lkb) ^ bx));
        acc[gg] = __builtin_amdgcn_mfma_f32_16x16x32_bf16(
            __builtin_bit_cast(bf16x8, araw[c]), bfv, acc[gg], 0, 0, 0);
      }
    }
    // ---- write k-partials to LDS (padded row 20 f32: conflict-free)
    const int zr0 = (lane >> 4) * 4;
#pragma unroll
    for (int gg = 0; gg < 4; ++gg)
#pragma unroll
      for (int r = 0; r < 4; ++r)
        zp[((wave * 4 + gg) * 16 + zr0 + r) * 20 + lr] = acc[gg][r];
    __syncthreads();
    // ---- reduce 4 k-partials + gates
    float zg0 = x0, zg1 = x1, zg2 = x2, zg3 = x3;
#pragma unroll
    for (int ww = 0; ww < 4; ++ww) {
      zg0 += zp[((ww * 4 + 0) * 16 + rrow) * 20 + du];
      zg1 += zp[((ww * 4 + 1) * 16 + rrow) * 20 + du];
      zg2 += zp[((ww * 4 + 2) * 16 + rrow) * 20 + du];
      zg3 += zp[((ww * 4 + 3) * 16 + rrow) * 20 + du];
    }
    const float ig = 1.f / (1.f + __expf(-zg0));
    const float fg = 1.f / (1.f + __expf(-zg1));
    const float gt = 1.f - 2.f / (1.f + __expf(2.f * zg2));
    const float og = 1.f / (1.f + __expf(-zg3));
    const float cn = fg * c_reg + ig * gt;
    const float hn = og * (1.f - 2.f / (1.f + __expf(2.f * cn)));
    if (idv != 0) { c_reg = cn; h_reg = hn; }
    const unsigned short hb16 = f2bf(h_reg);
    // ---- publish h(t+1) (LLC write-through), then epoch flag after drain+barrier
    {
      unsigned short* p = hbuf + (size_t)((t & 1) ^ 1) * 65536 + (size_t)brow * 1024 + unit;
      asm volatile("global_store_short %0, %1, off sc0 sc1"
                   :: "v"(p), "v"((unsigned)hb16) : "memory");
    }
    if (LAYER == 0)
      seqbf[((size_t)brow * 128 + t) * 1024 + unit] = hb16;
    else
      seqf[((size_t)brow * 128 + t) * 1024 + unit] = h_reg;
    asm volatile("s_waitcnt vmcnt(0)" ::: "memory");
    __syncthreads();  // all lanes drained; also WAR-protects zp for next step
    if (tid == 0)
      __hip_atomic_store(&flags[w * 16], (unsigned)(t + 2), __ATOMIC_RELAXED,
                         __HIP_MEMORY_SCOPE_AGENT);
  }
  hfin[(size_t)brow * 1024 + unit] = h_reg;
  cfin[(size_t)brow * 1024 + unit] = c_reg;
}

extern "C" void kernel_launch(void* const* d_in, const int* in_sizes, int n_in,
                              void* d_out, int out_size, void* d_ws, size_t ws_size,
                              hipStream_t stream) {
  (void)in_sizes; (void)n_in; (void)out_size; (void)ws_size;
  const int* ids = (const int*)d_in[0];
  const float* emb = (const float*)d_in[1];
  const float* Wx0 = (const float*)d_in[2];
  const float* Wh0 = (const float*)d_in[3];
  const float* b0 = (const float*)d_in[4];
  const float* Wx1 = (const float*)d_in[5];
  const float* Wh1 = (const float*)d_in[6];
  const float* b1 = (const float*)d_in[7];
  float* out = (float*)d_out;

  char* ws = (char*)d_ws;
  const size_t SZ_WT = (size_t)4096 * 1024 * 2;  // 8 MiB
  unsigned short* WxT0 = (unsigned short*)(ws);
  unsigned short* WhT0 = (unsigned short*)(ws + SZ_WT);
  unsigned short* WxT1 = (unsigned short*)(ws + 2 * SZ_WT);
  unsigned short* WhT1 = (unsigned short*)(ws + 3 * SZ_WT);
  unsigned short* xbf = (unsigned short*)(ws + 4 * SZ_WT);                  // 16 MiB
  unsigned short* seq0 = (unsigned short*)(ws + 4 * SZ_WT + 16777216);      // 16 MiB
  unsigned short* hbuf = (unsigned short*)(ws + 4 * SZ_WT + 2 * 16777216);  // 256 KiB
  unsigned* flags = (unsigned*)(ws + 4 * SZ_WT + 2 * 16777216 + 262144);    // 16 KiB
  float* xpb = (float*)(ws + 4 * SZ_WT + 2 * 16777216 + 262144 + 16384);    // 128 MiB

  float* h0f = out + 8388608;
  float* c0f = h0f + 65536;
  float* h1f = c0f + 65536;
  float* c1f = h1f + 65536;

  transpose_cast_k<<<dim3(128, 32), dim3(256), 0, stream>>>(Wx0, WxT0);
  transpose_cast_k<<<dim3(128, 32), dim3(256), 0, stream>>>(Wh0, WhT0);
  transpose_cast_k<<<dim3(128, 32), dim3(256), 0, stream>>>(Wx1, WxT1);
  transpose_cast_k<<<dim3(128, 32), dim3(256), 0, stream>>>(Wh1, WhT1);
  embed_gather_k<<<dim3(8192), dim3(256), 0, stream>>>(ids, emb, xbf);
  gemm_bt_k<<<dim3(2048), dim3(256), 0, stream>>>(xbf, WxT0, b0, xpb);

  hipFuncSetAttribute(reinterpret_cast<const void*>(&lstm_layer_k<0>),
                      hipFuncAttributeMaxDynamicSharedMemorySize, 151552);
  hipFuncSetAttribute(reinterpret_cast<const void*>(&lstm_layer_k<1>),
                      hipFuncAttributeMaxDynamicSharedMemorySize, 151552);

  hipMemsetAsync(flags, 0, 16384, stream);
  {
    const float* xp_p = xpb;
    const unsigned short* wht = WhT0;
    const int* ids_p = ids;
    unsigned short* hb_p = hbuf;
    unsigned short* sb_p = seq0;
    float* sf_p = nullptr;
    float* hf_p = h0f;
    float* cf_p = c0f;
    unsigned* fl_p = flags;
    void* ka[9] = {&xp_p, &wht, &ids_p, &hb_p, &sb_p, &sf_p, &hf_p, &cf_p, &fl_p};
    hipLaunchCooperativeKernel(reinterpret_cast<const void*>(&lstm_layer_k<0>),
                               dim3(256), dim3(256), ka, 151552u, stream);
  }
  gemm_bt_k<<<dim3(2048), dim3(256), 0, stream>>>(seq0, WxT1, b1, xpb);
  hipMemsetAsync(flags, 0, 16384, stream);
  {
    const float* xp_p = xpb;
    const unsigned short* wht = WhT1;
    const int* ids_p = ids;
    unsigned short* hb_p = hbuf;
    unsigned short* sb_p = nullptr;
    float* sf_p = out;
    float* hf_p = h1f;
    float* cf_p = c1f;
    unsigned* fl_p = flags;
    void* ka[9] = {&xp_p, &wht, &ids_p, &hb_p, &sb_p, &sf_p, &hf_p, &cf_p, &fl_p};
    hipLaunchCooperativeKernel(reinterpret_cast<const void*>(&lstm_layer_k<1>),
                               dim3(256), dim3(256), ka, 151552u, stream);
  }
}